// Round 4
// baseline (11488.007 us; speedup 1.0000x reference)
//
#include <hip/hip_runtime.h>
#include <hip/hip_bf16.h>
#include <hip/hip_cooperative_groups.h>

namespace cg = cooperative_groups;

#define Bb 8
#define Ss 128
#define Hh 1024
#define Vv 32000
#define NROWS (Bb*Ss)   // 1024

typedef __bf16 bf16;
typedef __bf16 v8bf __attribute__((ext_vector_type(8)));
typedef __bf16 v4bf __attribute__((ext_vector_type(4)));
typedef __bf16 v2bf __attribute__((ext_vector_type(2)));
typedef float  f32x4 __attribute__((ext_vector_type(4)));

// ---------------------------------------------------------------------------
// Pack row-major f32 W[K][N] -> frag-linear bf16 (validated layout):
//   Wp[((c*(N/16) + s)*64 + l)*8 + e] = W[32c + 8*(l>>4) + e][16s + (l&15)]
// via LDS transpose: coalesced float4 reads, coalesced 16B v8bf writes.
// grid (K/32, N/256), block 256.
// ---------------------------------------------------------------------------
__global__ __launch_bounds__(256) void k_pack2(
    const float* __restrict__ W, bf16* __restrict__ Wp, int N)
{
    __shared__ bf16 lt[32][258];
    const int c = blockIdx.x, n0 = blockIdx.y << 8;
    const int Ns = N >> 4, s0 = n0 >> 4;
    const int tid = threadIdx.x;
    #pragma unroll
    for (int i = 0; i < 8; ++i) {
        int q = (i << 8) + tid;          // 2048 float4 slots = 32 rows x 64
        int kk = q >> 6, nq = q & 63;
        float4 v = *reinterpret_cast<const float4*>(
            &W[(size_t)((c << 5) + kk) * N + n0 + (nq << 2)]);
        lt[kk][(nq << 2) + 0] = (bf16)v.x;
        lt[kk][(nq << 2) + 1] = (bf16)v.y;
        lt[kk][(nq << 2) + 2] = (bf16)v.z;
        lt[kk][(nq << 2) + 3] = (bf16)v.w;
    }
    __syncthreads();
    #pragma unroll
    for (int u = 0; u < 4; ++u) {
        int p = (u << 8) + tid;          // 1024 (s,l) pairs
        int s = p >> 6, ll = p & 63;
        v8bf pk;
        #pragma unroll
        for (int e = 0; e < 8; ++e)
            pk[e] = lt[((ll >> 4) << 3) + e][(s << 4) + (ll & 15)];
        *reinterpret_cast<v8bf*>(
            &Wp[((((size_t)c * Ns + s0 + s) << 6) + ll) << 3]) = pk;
    }
}

// ---------------------------------------------------------------------------
// Generic rows x 1024 GEMM, K=1024 (fp32).
// MODE 0: A-row = emb[labels[row]] (gather), relu, + bf16 mirror out.
// MODE 1: A-row = A[row] (direct), exact gelu.
// ---------------------------------------------------------------------------
template<int MODE>
__global__ __launch_bounds__(256) void k_gemm1024(
    const int* __restrict__ labels, const float* __restrict__ A,
    const float* __restrict__ W, const float* __restrict__ bias,
    float* __restrict__ out, bf16* __restrict__ outb)
{
    __shared__ float Als[16][32];
    const int tid  = threadIdx.x;
    const int jj   = (blockIdx.x << 8) + ((tid & 63) << 2);
    const int rg   = tid >> 6;
    const int row0 = blockIdx.y << 4;
    float acc[4][4] = {};
    for (int k0 = 0; k0 < Hh; k0 += 32) {
        __syncthreads();
        #pragma unroll
        for (int u = 0; u < 2; ++u) {
            int i = (u << 8) + tid;
            int r = i >> 5, kk = i & 31;
            int row = row0 + r;
            size_t base = (MODE == 0) ? (size_t)labels[row] * Hh : (size_t)row * Hh;
            Als[r][kk] = A[base + k0 + kk];
        }
        __syncthreads();
        #pragma unroll 8
        for (int kk = 0; kk < 32; ++kk) {
            const float4 w4 = *reinterpret_cast<const float4*>(&W[(size_t)(k0 + kk) * Hh + jj]);
            #pragma unroll
            for (int i = 0; i < 4; ++i) {
                float a = Als[(rg << 2) + i][kk];
                acc[i][0] = fmaf(a, w4.x, acc[i][0]);
                acc[i][1] = fmaf(a, w4.y, acc[i][1]);
                acc[i][2] = fmaf(a, w4.z, acc[i][2]);
                acc[i][3] = fmaf(a, w4.w, acc[i][3]);
            }
        }
    }
    const float4 b4 = *reinterpret_cast<const float4*>(&bias[jj]);
    #pragma unroll
    for (int i = 0; i < 4; ++i) {
        int row = row0 + (rg << 2) + i;
        float v[4] = {acc[i][0] + b4.x, acc[i][1] + b4.y, acc[i][2] + b4.z, acc[i][3] + b4.w};
        float o[4];
        #pragma unroll
        for (int j = 0; j < 4; ++j) {
            if (MODE == 0) o[j] = fmaxf(v[j], 0.f);
            else           o[j] = 0.5f * v[j] * (1.f + erff(v[j] * 0.70710678f));
        }
        *reinterpret_cast<float4*>(&out[(size_t)row * Hh + jj]) =
            make_float4(o[0], o[1], o[2], o[3]);
        if (MODE == 0) {
            v4bf ob; ob[0] = (bf16)o[0]; ob[1] = (bf16)o[1];
            ob[2] = (bf16)o[2]; ob[3] = (bf16)o[3];
            *reinterpret_cast<v4bf*>(&outb[(size_t)row * Hh + jj]) = ob;
        }
    }
}

// ---------------------------------------------------------------------------
// Cooperative persistent scan: all 126 steps in one launch.
// Per step m (rows t in [m+1,127], flattened rho = 8*(t-t0)+b):
//  Phase 1: tiles 64 rows x 64 cols; 8 waves (wm=w>>1 rows, wn=w&1 cols),
//    wave tile 16x32 = 2 frags x 64 K-chunks of MFMA 16x16x32.
//    pre = 0.1*relu(acc+b_sani) + hf (skip, in-place update of hf);
//    LN partials (s1,s2 per row per 64-col block) -> prt[row][16][2].
//  grid.sync()
//  Phase 2: one row per (block,u): apply LN from 16 partials; write hf (in
//    place), bf16 pong mirror, and outState row when t==m+1.
//  grid.sync()
// grid 256 blocks x 512 threads (co-resident; 1 block/CU).
// ---------------------------------------------------------------------------
__global__ __launch_bounds__(512, 1) void k_scan_coop(
    bf16* __restrict__ hb0, bf16* __restrict__ hb1, float* __restrict__ hf,
    const bf16* __restrict__ Wp, const float* __restrict__ bias,
    const float* __restrict__ lng, const float* __restrict__ lnb,
    float* __restrict__ os, float* __restrict__ prt)
{
    cg::grid_group grid = cg::this_grid();
    const int tid = threadIdx.x, l = tid & 63, w = tid >> 6;
    const int wm = w >> 1, wn = w & 1;
    const int lo = l & 15, hi = l >> 4;
    const int gblk = blockIdx.x;
    __shared__ float ls[64][2][2];

    for (int m = 0; m < Ss - 2; ++m) {
        const int nt  = Ss - 1 - m;
        const int nrb = (nt + 7) >> 3;
        const bf16* hbs = (m & 1) ? hb1 : hb0;
        bf16*       hbd = (m & 1) ? hb0 : hb1;

        if (gblk < (nrb << 4)) {
            const int cb = gblk & 15, rb = gblk >> 4;
            const int t0 = m + 1 + (rb << 3);
            // ---- MFMA phase ----
            int tA = t0 + (wm << 1) + (lo >> 3); if (tA > Ss - 1) tA = Ss - 1;
            const bf16* pA = hbs + ((((size_t)((lo & 7) << 7)) + tA - 1) << 10) + (hi << 3);
            const int s0 = (cb << 2) + (wn << 1);
            const bf16* pB = Wp + ((size_t)s0 << 9) + (l << 3);
            f32x4 acc0 = {}, acc1 = {};
            for (int c = 0; c < 64; ++c) {
                v8bf a  = *reinterpret_cast<const v8bf*>(pA + (c << 5));
                v8bf b0 = *reinterpret_cast<const v8bf*>(pB + ((size_t)c << 15));
                v8bf b1 = *reinterpret_cast<const v8bf*>(pB + ((size_t)c << 15) + 512);
                acc0 = __builtin_amdgcn_mfma_f32_16x16x32_bf16(a, b0, acc0, 0, 0, 0);
                acc1 = __builtin_amdgcn_mfma_f32_16x16x32_bf16(a, b1, acc1, 0, 0, 0);
            }
            // ---- epilogue: skip + relu, in-place hf, LN partials ----
            const int n0 = (cb << 6) + (wn << 5);
            const int col0 = n0 + lo, col1 = col0 + 16;
            const float bs0 = bias[col0], bs1 = bias[col1];
            float s1v[4], s2v[4];
            #pragma unroll
            for (int j = 0; j < 4; ++j) {
                const int fr = (hi << 2) + j;
                const int t  = t0 + (wm << 1) + (fr >> 3);
                const int bb = fr & 7;
                const int tc = t > Ss - 1 ? Ss - 1 : t;
                const size_t ro = (((size_t)(bb << 7)) + tc) << 10;
                float p0 = 0.1f * fmaxf(acc0[j] + bs0, 0.f) + hf[ro + col0];
                float p1 = 0.1f * fmaxf(acc1[j] + bs1, 0.f) + hf[ro + col1];
                if (t <= Ss - 1) { hf[ro + col0] = p0; hf[ro + col1] = p1; }
                s1v[j] = p0 + p1; s2v[j] = p0 * p0 + p1 * p1;
            }
            #pragma unroll
            for (int off = 1; off < 16; off <<= 1) {
                #pragma unroll
                for (int j = 0; j < 4; ++j) {
                    s1v[j] += __shfl_xor(s1v[j], off);
                    s2v[j] += __shfl_xor(s2v[j], off);
                }
            }
            if (lo == 0) {
                #pragma unroll
                for (int j = 0; j < 4; ++j) {
                    ls[(wm << 4) + (hi << 2) + j][wn][0] = s1v[j];
                    ls[(wm << 4) + (hi << 2) + j][wn][1] = s2v[j];
                }
            }
        }
        __syncthreads();
        if (gblk < (nrb << 4) && tid < 64) {
            const int cb = gblk & 15, rb = gblk >> 4;
            const int t0 = m + 1 + (rb << 3);
            const int t  = t0 + (tid >> 3), bb = tid & 7;
            if (t <= Ss - 1) {
                float* pp = prt + ((((size_t)(bb << 7) + t) << 5) + (cb << 1));
                pp[0] = ls[tid][0][0] + ls[tid][1][0];
                pp[1] = ls[tid][0][1] + ls[tid][1][1];
            }
        }
        grid.sync();

        // ---- Phase 2: LayerNorm rows ----
        #pragma unroll
        for (int u = 0; u < 4; ++u) {
            const int ridx = (u << 8) + gblk;
            if (ridx < (nt << 3)) {
                const int t = m + 1 + (ridx >> 3), bb = ridx & 7;
                const size_t ro = (((size_t)(bb << 7)) + t) << 10;
                const float* pp = prt + (((size_t)(bb << 7) + t) << 5);
                float s1 = 0.f, s2 = 0.f;
                #pragma unroll
                for (int q = 0; q < 16; ++q) { s1 += pp[q << 1]; s2 += pp[(q << 1) + 1]; }
                const float mu = s1 * (1.f / Hh);
                const float rs = rsqrtf(s2 * (1.f / Hh) - mu * mu + 1e-5f);
                const float2 v  = *reinterpret_cast<const float2*>(hf + ro + (tid << 1));
                const float2 gv = *reinterpret_cast<const float2*>(lng + (tid << 1));
                const float2 bv = *reinterpret_cast<const float2*>(lnb + (tid << 1));
                const float o0 = (v.x - mu) * rs * gv.x + bv.x;
                const float o1 = (v.y - mu) * rs * gv.y + bv.y;
                *reinterpret_cast<float2*>(hf + ro + (tid << 1)) = make_float2(o0, o1);
                v2bf ob; ob[0] = (bf16)o0; ob[1] = (bf16)o1;
                *reinterpret_cast<v2bf*>(hbd + ro + (tid << 1)) = ob;
                if (t == m + 1)
                    *reinterpret_cast<float2*>(
                        os + ((((size_t)(bb << 7)) + m) << 10) + (tid << 1)) = make_float2(o0, o1);
            }
        }
        grid.sync();
    }
}

// Head LayerNorm in place (eps 1e-12) + optional bf16 mirror. grid 1024.
__global__ __launch_bounds__(256) void k_ln_rows2(
    float* __restrict__ buf, const float* __restrict__ g,
    const float* __restrict__ be, bf16* __restrict__ ybb)
{
    const int tid = threadIdx.x;
    float* rowp = buf + (size_t)blockIdx.x * Hh;
    float4 v = *reinterpret_cast<float4*>(&rowp[tid << 2]);
    float s1 = v.x + v.y + v.z + v.w;
    float s2 = v.x*v.x + v.y*v.y + v.z*v.z + v.w*v.w;
    #pragma unroll
    for (int off = 1; off < 64; off <<= 1) { s1 += __shfl_xor(s1, off); s2 += __shfl_xor(s2, off); }
    __shared__ float r1[4], r2[4];
    if ((tid & 63) == 0) { r1[tid >> 6] = s1; r2[tid >> 6] = s2; }
    __syncthreads();
    s1 = r1[0] + r1[1] + r1[2] + r1[3];
    s2 = r2[0] + r2[1] + r2[2] + r2[3];
    const float mu = s1 * (1.f / Hh);
    const float rs = rsqrtf(s2 * (1.f / Hh) - mu * mu + 1e-12f);
    const float4 g4 = *reinterpret_cast<const float4*>(&g[tid << 2]);
    const float4 b4 = *reinterpret_cast<const float4*>(&be[tid << 2]);
    float4 o;
    o.x = (v.x - mu) * rs * g4.x + b4.x;
    o.y = (v.y - mu) * rs * g4.y + b4.y;
    o.z = (v.z - mu) * rs * g4.z + b4.z;
    o.w = (v.w - mu) * rs * g4.w + b4.w;
    *reinterpret_cast<float4*>(&rowp[tid << 2]) = o;
    if (ybb) {
        v4bf ob; ob[0] = (bf16)o.x; ob[1] = (bf16)o.y; ob[2] = (bf16)o.z; ob[3] = (bf16)o.w;
        *reinterpret_cast<v4bf*>(&ybb[(size_t)blockIdx.x * Hh + (tid << 2)]) = ob;
    }
}

// ---------------------------------------------------------------------------
// Decoder bf16 MFMA (fast path): C[1024][32000] = ybb @ Wdec + bd.
// grid (250, 4), block 512. No LDS/barriers.
// ---------------------------------------------------------------------------
__global__ __launch_bounds__(512) void k_dec_mm(
    const bf16* __restrict__ A, const bf16* __restrict__ Wp,
    const float* __restrict__ bd, float* __restrict__ C)
{
    const int tid = threadIdx.x, l = tid & 63, w = tid >> 6;
    const int wr = w >> 1, wc = w & 1;
    const int n0 = (blockIdx.x << 7) + (wc << 6);
    const int r0 = (blockIdx.y << 8) + (wr << 6);
    const bf16* pA = A + (((size_t)(r0 + (l & 15))) << 10) + ((l >> 4) << 3);
    const int sb = (blockIdx.x << 3) + (wc << 2);
    const bf16* pB = Wp + (((size_t)(sb << 6) + l) << 3);

    f32x4 acc[4][4] = {};
    for (int c = 0; c < 32; ++c) {
        v8bf af[4], bfr[4];
        #pragma unroll
        for (int mi = 0; mi < 4; ++mi)
            af[mi] = *reinterpret_cast<const v8bf*>(pA + (((size_t)mi << 4) << 10) + (c << 5));
        #pragma unroll
        for (int ni = 0; ni < 4; ++ni)
            bfr[ni] = *reinterpret_cast<const v8bf*>(pB + (size_t)c * 1024000 + (ni << 9));
        #pragma unroll
        for (int mi = 0; mi < 4; ++mi)
            #pragma unroll
            for (int ni = 0; ni < 4; ++ni)
                acc[mi][ni] = __builtin_amdgcn_mfma_f32_16x16x32_bf16(af[mi], bfr[ni], acc[mi][ni], 0, 0, 0);
    }

    const int r4 = (l >> 4) << 2, cn = l & 15;
    #pragma unroll
    for (int mi = 0; mi < 4; ++mi) {
        #pragma unroll
        for (int ni = 0; ni < 4; ++ni) {
            const int col = n0 + (ni << 4) + cn;
            const float bj = bd[col];
            #pragma unroll
            for (int j = 0; j < 4; ++j) {
                const int row = r0 + (mi << 4) + r4 + j;
                C[(size_t)row * Vv + col] = acc[mi][ni][j] + bj;
            }
        }
    }
}

// Decoder fp32 fallback (small-ws path). grid (500,16).
__global__ __launch_bounds__(256) void k_decoder(
    const float* __restrict__ A, const float* __restrict__ Wd,
    const float* __restrict__ bd, float* __restrict__ C)
{
    __shared__ float As[16][68];
    __shared__ float Bs[16][68];
    const int tid = threadIdx.x;
    const int tx = tid & 15, ty = tid >> 4;
    const int n0 = blockIdx.x << 6, r0 = blockIdx.y << 6;
    float acc[4][4] = {};
    for (int k0 = 0; k0 < Hh; k0 += 16) {
        __syncthreads();
        #pragma unroll
        for (int u = 0; u < 4; ++u) {
            int e = (u << 8) + tid;
            int r = e >> 4, kk = e & 15;
            As[kk][r] = A[(size_t)(r0 + r) * Hh + k0 + kk];
        }
        #pragma unroll
        for (int u = 0; u < 4; ++u) {
            int e = (u << 8) + tid;
            int kk = e >> 6, nn = e & 63;
            Bs[kk][nn] = Wd[(size_t)(k0 + kk) * Vv + n0 + nn];
        }
        __syncthreads();
        #pragma unroll
        for (int kk = 0; kk < 16; ++kk) {
            float a[4], wv[4];
            #pragma unroll
            for (int i = 0; i < 4; ++i) a[i] = As[kk][ty + (i << 4)];
            #pragma unroll
            for (int j = 0; j < 4; ++j) wv[j] = Bs[kk][tx + (j << 4)];
            #pragma unroll
            for (int i = 0; i < 4; ++i)
                #pragma unroll
                for (int j = 0; j < 4; ++j)
                    acc[i][j] = fmaf(a[i], wv[j], acc[i][j]);
        }
    }
    #pragma unroll
    for (int j = 0; j < 4; ++j) {
        const float bj = bd[n0 + tx + (j << 4)];
        #pragma unroll
        for (int i = 0; i < 4; ++i)
            C[(size_t)(r0 + ty + (i << 4)) * Vv + n0 + tx + (j << 4)] = acc[i][j] + bj;
    }
}

// ---------------------------------------------------------------------------
// CE loss.
// ---------------------------------------------------------------------------
__global__ __launch_bounds__(256) void k_loss_row(
    const float* __restrict__ logits, const int* __restrict__ labels,
    float* __restrict__ partial)
{
    const int row = blockIdx.x;
    const float* lr = logits + (size_t)row * Vv;
    float m = -3.4e38f, s = 0.f;
    for (int i = threadIdx.x; i < Vv; i += 256) {
        float v = lr[i];
        float nm = fmaxf(m, v);
        s = s * expf(m - nm) + expf(v - nm);
        m = nm;
    }
    #pragma unroll
    for (int off = 1; off < 64; off <<= 1) {
        float om = __shfl_xor(m, off);
        float osv = __shfl_xor(s, off);
        float nm = fmaxf(m, om);
        s = s * expf(m - nm) + osv * expf(om - nm);
        m = nm;
    }
    __shared__ float lm[4], lsum[4];
    const int wid = threadIdx.x >> 6;
    if ((threadIdx.x & 63) == 0) { lm[wid] = m; lsum[wid] = s; }
    __syncthreads();
    if (threadIdx.x == 0) {
        float M = lm[0], Sv = lsum[0];
        #pragma unroll
        for (int ww = 1; ww < 4; ++ww) {
            float nm = fmaxf(M, lm[ww]);
            Sv = Sv * expf(M - nm) + lsum[ww] * expf(lm[ww] - nm);
            M = nm;
        }
        partial[row] = (M + logf(Sv)) - lr[labels[row]];
    }
}

__global__ __launch_bounds__(256) void k_loss_final(
    const float* __restrict__ partial, float* __restrict__ out0)
{
    float s = partial[threadIdx.x] + partial[threadIdx.x + 256]
            + partial[threadIdx.x + 512] + partial[threadIdx.x + 768];
    #pragma unroll
    for (int off = 1; off < 64; off <<= 1) s += __shfl_xor(s, off);
    __shared__ float red[4];
    if ((threadIdx.x & 63) == 0) red[threadIdx.x >> 6] = s;
    __syncthreads();
    if (threadIdx.x == 0) out0[0] = (red[0] + red[1] + red[2] + red[3]) * (1.f / NROWS);
}

// ---------------------------------------------------------------------------
extern "C" void kernel_launch(void* const* d_in, const int* in_sizes, int n_in,
                              void* d_out, int out_size, void* d_ws, size_t ws_size,
                              hipStream_t stream)
{
    const int*   labels  = (const int*)d_in[0];
    const float* emb     = (const float*)d_in[1];
    const float* W_in    = (const float*)d_in[2];
    const float* b_in    = (const float*)d_in[3];
    const float* W_sani  = (const float*)d_in[4];
    const float* b_sani  = (const float*)d_in[5];
    const float* ln_g    = (const float*)d_in[6];
    const float* ln_b    = (const float*)d_in[7];
    const float* W_dense = (const float*)d_in[8];
    const float* b_dense = (const float*)d_in[9];
    const float* ln2_g   = (const float*)d_in[10];
    const float* ln2_b   = (const float*)d_in[11];
    const float* W_dec   = (const float*)d_in[12];
    const float* b_dec   = (const float*)d_in[13];
    float* out    = (float*)d_out;
    float* logits = out + 1;

    const size_t NH = (size_t)NROWS * Hh;                 // 1M elems
    const size_t WDP_ELEMS = (size_t)32 * 2000 * 64 * 8;  // 32.768M bf16

    // out-scratch (dead before logits are written):
    float* S   = out + 8;
    float* hf  = S;                          // 1 NH f32 (in-place h state)
    float* os  = S + NH;                     // 1 NH f32 (outputState)
    float* ybf = S + 2 * NH;                 // 1 NH f32 (head dense out, fast path)
    bf16*  Wp  = (bf16*)(S + 3 * NH);        // 2M bf16 (sani packed)
    bf16*  hb0 = (bf16*)(S + 4 * NH);        // 1M bf16 (h mirror ping)
    bf16*  hb1 = hb0 + NH;                   // 1M bf16 (h mirror pong)
    float* prt = S + 5 * NH;                 // 32K f32 (LN partials)

    const bool fast = ws_size >= WDP_ELEMS * 2 + NH * 2 + 8192;
    bf16 *Wdp = nullptr, *ybb = nullptr;
    float *yb, *pt;
    float* wsf = (float*)d_ws;
    if (fast) {
        Wdp = (bf16*)d_ws;
        ybb = Wdp + WDP_ELEMS;
        pt  = (float*)(ybb + NH);
        yb  = ybf;
    } else {
        yb = wsf;
        pt = wsf + NH;
    }

    k_pack2<<<dim3(64, 4), 256, 0, stream>>>(W_sani, Wp, Hh);
    if (fast)
        k_pack2<<<dim3(32, 125), 256, 0, stream>>>(W_dec, Wdp, Vv);

    hipMemsetAsync(os, 0, NH * sizeof(float), stream);   // rows 126/127 stay 0
    k_gemm1024<0><<<dim3(4, 64), 256, 0, stream>>>(labels, emb, W_in, b_in, hf, hb0);

    {
        void* args[] = {(void*)&hb0, (void*)&hb1, (void*)&hf, (void*)&Wp,
                        (void*)&b_sani, (void*)&ln_g, (void*)&ln_b,
                        (void*)&os, (void*)&prt};
        hipLaunchCooperativeKernel((void*)k_scan_coop, dim3(256), dim3(512),
                                   args, 0, stream);
    }

    k_gemm1024<1><<<dim3(4, 64), 256, 0, stream>>>(nullptr, os, W_dense, b_dense, yb, nullptr);
    k_ln_rows2<<<NROWS, 256, 0, stream>>>(yb, ln2_g, ln2_b, ybb);
    if (fast)
        k_dec_mm<<<dim3(250, 4), 512, 0, stream>>>(ybb, Wdp, b_dec, logits);
    else
        k_decoder<<<dim3(Vv / 64, NROWS / 64), 256, 0, stream>>>(yb, W_dec, b_dec, logits);
    k_loss_row<<<NROWS, 256, 0, stream>>>(logits, labels, pt);
    k_loss_final<<<1, 256, 0, stream>>>(pt, out);
}

// Round 5
// 3963.433 us; speedup vs baseline: 2.8985x; 2.8985x over previous
//
#include <hip/hip_runtime.h>
#include <hip/hip_bf16.h>

#define Bb 8
#define Ss 128
#define Hh 1024
#define Vv 32000
#define NROWS (Bb*Ss)   // 1024

typedef __bf16 bf16;
typedef __bf16 v8bf __attribute__((ext_vector_type(8)));
typedef __bf16 v4bf __attribute__((ext_vector_type(4)));
typedef float  f32x4 __attribute__((ext_vector_type(4)));

// ---------------------------------------------------------------------------
// Pack row-major f32 W[K][N] -> frag-linear bf16 (validated layout):
//   Wp[((c*(N/16) + s)*64 + l)*8 + e] = W[32c + 8*(l>>4) + e][16s + (l&15)]
// optionally scaling row k by gscale[k & 1023] (LN-gamma fold).
// grid (K/32, N/256), block 256.
// ---------------------------------------------------------------------------
__global__ __launch_bounds__(256) void k_pack2(
    const float* __restrict__ W, bf16* __restrict__ Wp, int N,
    const float* __restrict__ gscale)
{
    __shared__ bf16 lt[32][258];
    const int c = blockIdx.x, n0 = blockIdx.y << 8;
    const int Ns = N >> 4, s0 = n0 >> 4;
    const int tid = threadIdx.x;
    #pragma unroll
    for (int i = 0; i < 8; ++i) {
        int q = (i << 8) + tid;          // 2048 float4 slots = 32 rows x 64
        int kk = q >> 6, nq = q & 63;
        float gs = gscale ? gscale[((c << 5) + kk) & 1023] : 1.0f;
        float4 v = *reinterpret_cast<const float4*>(
            &W[(size_t)((c << 5) + kk) * N + n0 + (nq << 2)]);
        lt[kk][(nq << 2) + 0] = (bf16)(v.x * gs);
        lt[kk][(nq << 2) + 1] = (bf16)(v.y * gs);
        lt[kk][(nq << 2) + 2] = (bf16)(v.z * gs);
        lt[kk][(nq << 2) + 3] = (bf16)(v.w * gs);
    }
    __syncthreads();
    #pragma unroll
    for (int u = 0; u < 4; ++u) {
        int p = (u << 8) + tid;          // 1024 (s,l) pairs
        int s = p >> 6, ll = p & 63;
        v8bf pk;
        #pragma unroll
        for (int e = 0; e < 8; ++e)
            pk[e] = lt[((ll >> 4) << 3) + e][(s << 4) + (ll & 15)];
        *reinterpret_cast<v8bf*>(
            &Wp[((((size_t)c * Ns + s0 + s) << 6) + ll) << 3]) = pk;
    }
}

// cbias[n] = b_sani[n] + sum_k W_sani[k][n] * lnb[k & 1023]. grid 4 x 256.
__global__ __launch_bounds__(256) void k_cbias(
    const float* __restrict__ W, const float* __restrict__ bs,
    const float* __restrict__ lnb, float* __restrict__ cbias)
{
    const int col = blockIdx.x * 256 + threadIdx.x;
    float s = bs[col];
    #pragma unroll 8
    for (int k = 0; k < 2 * Hh; ++k)
        s = fmaf(W[(size_t)k * Hh + col], lnb[k & (Hh - 1)], s);
    cbias[col] = s;
}

// ---------------------------------------------------------------------------
// Generic rows x 1024 GEMM, K=1024 (fp32).
// MODE 0: A-row = emb[labels[row]] (gather), relu, + bf16 mirror out.
// MODE 1: A-row = A[row] (direct), exact gelu.
// ---------------------------------------------------------------------------
template<int MODE>
__global__ __launch_bounds__(256) void k_gemm1024(
    const int* __restrict__ labels, const float* __restrict__ A,
    const float* __restrict__ W, const float* __restrict__ bias,
    float* __restrict__ out, bf16* __restrict__ outb)
{
    __shared__ float Als[16][32];
    const int tid  = threadIdx.x;
    const int jj   = (blockIdx.x << 8) + ((tid & 63) << 2);
    const int rg   = tid >> 6;
    const int row0 = blockIdx.y << 4;
    float acc[4][4] = {};
    for (int k0 = 0; k0 < Hh; k0 += 32) {
        __syncthreads();
        #pragma unroll
        for (int u = 0; u < 2; ++u) {
            int i = (u << 8) + tid;
            int r = i >> 5, kk = i & 31;
            int row = row0 + r;
            size_t base = (MODE == 0) ? (size_t)labels[row] * Hh : (size_t)row * Hh;
            Als[r][kk] = A[base + k0 + kk];
        }
        __syncthreads();
        #pragma unroll 8
        for (int kk = 0; kk < 32; ++kk) {
            const float4 w4 = *reinterpret_cast<const float4*>(&W[(size_t)(k0 + kk) * Hh + jj]);
            #pragma unroll
            for (int i = 0; i < 4; ++i) {
                float a = Als[(rg << 2) + i][kk];
                acc[i][0] = fmaf(a, w4.x, acc[i][0]);
                acc[i][1] = fmaf(a, w4.y, acc[i][1]);
                acc[i][2] = fmaf(a, w4.z, acc[i][2]);
                acc[i][3] = fmaf(a, w4.w, acc[i][3]);
            }
        }
    }
    const float4 b4 = *reinterpret_cast<const float4*>(&bias[jj]);
    #pragma unroll
    for (int i = 0; i < 4; ++i) {
        int row = row0 + (rg << 2) + i;
        float v[4] = {acc[i][0] + b4.x, acc[i][1] + b4.y, acc[i][2] + b4.z, acc[i][3] + b4.w};
        float o[4];
        #pragma unroll
        for (int j = 0; j < 4; ++j) {
            if (MODE == 0) o[j] = fmaxf(v[j], 0.f);
            else           o[j] = 0.5f * v[j] * (1.f + erff(v[j] * 0.70710678f));
        }
        *reinterpret_cast<float4*>(&out[(size_t)row * Hh + jj]) =
            make_float4(o[0], o[1], o[2], o[3]);
        if (MODE == 0) {
            v4bf ob; ob[0] = (bf16)o[0]; ob[1] = (bf16)o[1];
            ob[2] = (bf16)o[2]; ob[3] = (bf16)o[3];
            *reinterpret_cast<v4bf*>(&outb[(size_t)row * Hh + jj]) = ob;
        }
    }
}

// ---------------------------------------------------------------------------
// Fused scan step m (one launch per step). h stored RAW (pre-LN) + per-row
// stats in ping-pong prt buffers; LN applied on the fly:
//   A-frag: z = (x - mu)*rs  (gamma folded into Wp', W.b_ln folded into cbias)
//   skip  : n = ((raw - mu)*rs)*g[col] + b[col]
//   pre_{m+1}[t] = 0.1*relu(z_window @ Wp' + cbias) + n_m[t],  t in [m+1,126]
// Epilogue stores raw pre (f32 + bf16 mirror) and (s1,s2) partials -> prtW.
// FIRST (m=0): inputs are h0 raw (no LN yet): plain Wp, plain b_sani, raw skip.
// Block 32 t-rows x 64 cols; 4 waves (wm rows, wn cols), wave tile 16x32.
// grid (16, ceil(nt/32), 8), block 256.   C/D map: col=l&15, row=4*(l>>4)+j.
// ---------------------------------------------------------------------------
template<int FIRST>
__global__ __launch_bounds__(256) void k_scan_fused(
    const bf16* __restrict__ hbA, const float* __restrict__ hfS,
    float* __restrict__ hfD, bf16* __restrict__ hbD,
    const bf16* __restrict__ Wp, const float* __restrict__ cb,
    const float* __restrict__ prtR, float* __restrict__ prtW,
    const float* __restrict__ lng, const float* __restrict__ lnb, int m)
{
    __shared__ float ls[32][2][2];
    const int tid = threadIdx.x, l = tid & 63, w = tid >> 6;
    const int wm = w >> 1, wn = w & 1;
    const int lo = l & 15, hi = l >> 4;
    const int bx = blockIdx.x;
    const int n0 = bx << 6;
    const int t0 = m + 1 + (blockIdx.y << 5);
    const int b  = blockIdx.z;

    int tA = t0 + (wm << 4) + lo; if (tA > 126) tA = 126;
    const bf16* pA = hbA + (((size_t)(b * Ss + tA - 1)) << 10) + (hi << 3);
    const int s0 = (bx << 2) + (wn << 1);
    const bf16* pB0 = Wp + (((size_t)(s0 << 6) + l) << 3);
    const bf16* pB1 = pB0 + 512;

    float rsA[2], cA[2], muE[4], rsE[4];
    if constexpr (!FIRST) {
        const int rr[2] = {tA - 1, tA};
        #pragma unroll
        for (int q = 0; q < 2; ++q) {
            const float4* pp = reinterpret_cast<const float4*>(
                prtR + (((size_t)(b * Ss + rr[q])) << 5));
            float s1 = 0.f, s2 = 0.f;
            #pragma unroll
            for (int i = 0; i < 8; ++i) { float4 v = pp[i]; s1 += v.x + v.z; s2 += v.y + v.w; }
            const float mu = s1 * (1.f / Hh);
            const float rs = rsqrtf(s2 * (1.f / Hh) - mu * mu + 1e-5f);
            rsA[q] = rs; cA[q] = -mu * rs;
        }
        #pragma unroll
        for (int j = 0; j < 4; ++j) {
            int tE = t0 + (wm << 4) + (hi << 2) + j; if (tE > 126) tE = 126;
            const float4* pp = reinterpret_cast<const float4*>(
                prtR + (((size_t)(b * Ss + tE)) << 5));
            float s1 = 0.f, s2 = 0.f;
            #pragma unroll
            for (int i = 0; i < 8; ++i) { float4 v = pp[i]; s1 += v.x + v.z; s2 += v.y + v.w; }
            muE[j] = s1 * (1.f / Hh);
            rsE[j] = rsqrtf(s2 * (1.f / Hh) - muE[j] * muE[j] + 1e-5f);
        }
    }

    f32x4 acc0 = {}, acc1 = {};
    #pragma unroll
    for (int half = 0; half < 2; ++half) {
        float rsel = 1.f, csel = 0.f;
        if constexpr (!FIRST) { rsel = rsA[half]; csel = cA[half]; }
        #pragma unroll 2
        for (int c = half << 5; c < (half << 5) + 32; ++c) {
            v8bf a;
            if constexpr (FIRST) {
                a = *reinterpret_cast<const v8bf*>(pA + (c << 5));
            } else {
                const uint4 ar = *reinterpret_cast<const uint4*>(pA + (c << 5));
                const unsigned u[4] = {ar.x, ar.y, ar.z, ar.w};
                #pragma unroll
                for (int i = 0; i < 4; ++i) {
                    float xl = __uint_as_float(u[i] << 16);
                    float xh = __uint_as_float(u[i] & 0xffff0000u);
                    a[2 * i]     = (bf16)fmaf(xl, rsel, csel);
                    a[2 * i + 1] = (bf16)fmaf(xh, rsel, csel);
                }
            }
            const v8bf b0 = *reinterpret_cast<const v8bf*>(pB0 + ((size_t)c << 15));
            const v8bf b1 = *reinterpret_cast<const v8bf*>(pB1 + ((size_t)c << 15));
            acc0 = __builtin_amdgcn_mfma_f32_16x16x32_bf16(a, b0, acc0, 0, 0, 0);
            acc1 = __builtin_amdgcn_mfma_f32_16x16x32_bf16(a, b1, acc1, 0, 0, 0);
        }
    }

    // epilogue
    float s1j[4] = {0.f, 0.f, 0.f, 0.f}, s2j[4] = {0.f, 0.f, 0.f, 0.f};
    #pragma unroll
    for (int ni = 0; ni < 2; ++ni) {
        const int col = n0 + (((wn << 1) + ni) << 4) + lo;
        const float cbv = cb[col];
        const float gv = lng[col], bv = lnb[col];
        #pragma unroll
        for (int j = 0; j < 4; ++j) {
            const int t = t0 + (wm << 4) + (hi << 2) + j;
            if (t <= 126) {
                const size_t off = (((size_t)(b * Ss + t)) << 10) + col;
                const float raw = hfS[off];
                float skip;
                if constexpr (FIRST) skip = raw;
                else skip = fmaf(fmaf(raw, rsE[j], -muE[j] * rsE[j]), gv, bv);
                const float av = (ni == 0) ? acc0[j] : acc1[j];
                const float pre = 0.1f * fmaxf(av + cbv, 0.f) + skip;
                hfD[off] = pre;
                hbD[off] = (bf16)pre;
                s1j[j] += pre; s2j[j] += pre * pre;
            }
        }
    }
    #pragma unroll
    for (int off = 1; off < 16; off <<= 1) {
        #pragma unroll
        for (int j = 0; j < 4; ++j) {
            s1j[j] += __shfl_xor(s1j[j], off);
            s2j[j] += __shfl_xor(s2j[j], off);
        }
    }
    if (lo == 0) {
        #pragma unroll
        for (int j = 0; j < 4; ++j) {
            ls[(wm << 4) + (hi << 2) + j][wn][0] = s1j[j];
            ls[(wm << 4) + (hi << 2) + j][wn][1] = s2j[j];
        }
    }
    __syncthreads();
    if (tid < 32) {
        const int t = t0 + tid;
        if (t <= 126) {
            const size_t base = (((size_t)(b * Ss + t)) << 5) + (bx << 1);
            prtW[base]     = ls[tid][0][0] + ls[tid][1][0];
            prtW[base + 1] = ls[tid][0][1] + ls[tid][1][1];
        }
    }
}

// ---------------------------------------------------------------------------
// Finalize outputState: os[b][m] = LN(hp_{(m+1)&1}[b][m+1]) using its stats.
// grid (126, 8), block 256 (4 cols each).
// ---------------------------------------------------------------------------
__global__ __launch_bounds__(256) void k_finish_os(
    const float* __restrict__ hpf0, const float* __restrict__ hpf1,
    const float* __restrict__ prt0, const float* __restrict__ prt1,
    const float* __restrict__ lng, const float* __restrict__ lnb,
    float* __restrict__ os)
{
    const int m = blockIdx.x, b = blockIdx.y, r = m + 1;
    const int p = r & 1;
    const float* hp = p ? hpf1 : hpf0;
    const float* pr = p ? prt1 : prt0;
    const float4* pp = reinterpret_cast<const float4*>(pr + (((size_t)(b * Ss + r)) << 5));
    float s1 = 0.f, s2 = 0.f;
    #pragma unroll
    for (int i = 0; i < 8; ++i) { float4 v = pp[i]; s1 += v.x + v.z; s2 += v.y + v.w; }
    const float mu = s1 * (1.f / Hh);
    const float rs = rsqrtf(s2 * (1.f / Hh) - mu * mu + 1e-5f);
    const int c4 = threadIdx.x << 2;
    const float4 raw = *reinterpret_cast<const float4*>(hp + (((size_t)(b * Ss + r)) << 10) + c4);
    const float4 g4 = *reinterpret_cast<const float4*>(&lng[c4]);
    const float4 b4 = *reinterpret_cast<const float4*>(&lnb[c4]);
    float4 o;
    o.x = fmaf((raw.x - mu) * rs, g4.x, b4.x);
    o.y = fmaf((raw.y - mu) * rs, g4.y, b4.y);
    o.z = fmaf((raw.z - mu) * rs, g4.z, b4.z);
    o.w = fmaf((raw.w - mu) * rs, g4.w, b4.w);
    *reinterpret_cast<float4*>(os + (((size_t)(b * Ss + m)) << 10) + c4) = o;
}

// Head LayerNorm in place (eps 1e-12) + optional bf16 mirror. grid 1024.
__global__ __launch_bounds__(256) void k_ln_rows2(
    float* __restrict__ buf, const float* __restrict__ g,
    const float* __restrict__ be, bf16* __restrict__ ybb)
{
    const int tid = threadIdx.x;
    float* rowp = buf + (size_t)blockIdx.x * Hh;
    float4 v = *reinterpret_cast<float4*>(&rowp[tid << 2]);
    float s1 = v.x + v.y + v.z + v.w;
    float s2 = v.x*v.x + v.y*v.y + v.z*v.z + v.w*v.w;
    #pragma unroll
    for (int off = 1; off < 64; off <<= 1) { s1 += __shfl_xor(s1, off); s2 += __shfl_xor(s2, off); }
    __shared__ float r1[4], r2[4];
    if ((tid & 63) == 0) { r1[tid >> 6] = s1; r2[tid >> 6] = s2; }
    __syncthreads();
    s1 = r1[0] + r1[1] + r1[2] + r1[3];
    s2 = r2[0] + r2[1] + r2[2] + r2[3];
    const float mu = s1 * (1.f / Hh);
    const float rs = rsqrtf(s2 * (1.f / Hh) - mu * mu + 1e-12f);
    const float4 g4 = *reinterpret_cast<const float4*>(&g[tid << 2]);
    const float4 b4 = *reinterpret_cast<const float4*>(&be[tid << 2]);
    float4 o;
    o.x = (v.x - mu) * rs * g4.x + b4.x;
    o.y = (v.y - mu) * rs * g4.y + b4.y;
    o.z = (v.z - mu) * rs * g4.z + b4.z;
    o.w = (v.w - mu) * rs * g4.w + b4.w;
    *reinterpret_cast<float4*>(&rowp[tid << 2]) = o;
    if (ybb) {
        v4bf ob; ob[0] = (bf16)o.x; ob[1] = (bf16)o.y; ob[2] = (bf16)o.z; ob[3] = (bf16)o.w;
        *reinterpret_cast<v4bf*>(&ybb[(size_t)blockIdx.x * Hh + (tid << 2)]) = ob;
    }
}

// ---------------------------------------------------------------------------
// Decoder bf16 MFMA (fast path): C[1024][32000] = ybb @ Wdec + bd.
// grid (250, 4), block 512. No LDS/barriers.
// ---------------------------------------------------------------------------
__global__ __launch_bounds__(512) void k_dec_mm(
    const bf16* __restrict__ A, const bf16* __restrict__ Wp,
    const float* __restrict__ bd, float* __restrict__ C)
{
    const int tid = threadIdx.x, l = tid & 63, w = tid >> 6;
    const int wr = w >> 1, wc = w & 1;
    const int n0 = (blockIdx.x << 7) + (wc << 6);
    const int r0 = (blockIdx.y << 8) + (wr << 6);
    const bf16* pA = A + (((size_t)(r0 + (l & 15))) << 10) + ((l >> 4) << 3);
    const int sb = (blockIdx.x << 3) + (wc << 2);
    const bf16* pB = Wp + (((size_t)(sb << 6) + l) << 3);

    f32x4 acc[4][4] = {};
    for (int c = 0; c < 32; ++c) {
        v8bf af[4], bfr[4];
        #pragma unroll
        for (int mi = 0; mi < 4; ++mi)
            af[mi] = *reinterpret_cast<const v8bf*>(pA + (((size_t)mi << 4) << 10) + (c << 5));
        #pragma unroll
        for (int ni = 0; ni < 4; ++ni)
            bfr[ni] = *reinterpret_cast<const v8bf*>(pB + (size_t)c * 1024000 + (ni << 9));
        #pragma unroll
        for (int mi = 0; mi < 4; ++mi)
            #pragma unroll
            for (int ni = 0; ni < 4; ++ni)
                acc[mi][ni] = __builtin_amdgcn_mfma_f32_16x16x32_bf16(af[mi], bfr[ni], acc[mi][ni], 0, 0, 0);
    }

    const int r4 = (l >> 4) << 2, cn = l & 15;
    #pragma unroll
    for (int mi = 0; mi < 4; ++mi) {
        #pragma unroll
        for (int ni = 0; ni < 4; ++ni) {
            const int col = n0 + (ni << 4) + cn;
            const float bj = bd[col];
            #pragma unroll
            for (int j = 0; j < 4; ++j) {
                const int row = r0 + (mi << 4) + r4 + j;
                C[(size_t)row * Vv + col] = acc[mi][ni][j] + bj;
            }
        }
    }
}

// Decoder fp32 fallback (small-ws path). grid (500,16).
__global__ __launch_bounds__(256) void k_decoder(
    const float* __restrict__ A, const float* __restrict__ Wd,
    const float* __restrict__ bd, float* __restrict__ C)
{
    __shared__ float As[16][68];
    __shared__ float Bs[16][68];
    const int tid = threadIdx.x;
    const int tx = tid & 15, ty = tid >> 4;
    const int n0 = blockIdx.x << 6, r0 = blockIdx.y << 6;
    float acc[4][4] = {};
    for (int k0 = 0; k0 < Hh; k0 += 16) {
        __syncthreads();
        #pragma unroll
        for (int u = 0; u < 4; ++u) {
            int e = (u << 8) + tid;
            int r = e >> 4, kk = e & 15;
            As[kk][r] = A[(size_t)(r0 + r) * Hh + k0 + kk];
        }
        #pragma unroll
        for (int u = 0; u < 4; ++u) {
            int e = (u << 8) + tid;
            int kk = e >> 6, nn = e & 63;
            Bs[kk][nn] = Wd[(size_t)(k0 + kk) * Vv + n0 + nn];
        }
        __syncthreads();
        #pragma unroll
        for (int kk = 0; kk < 16; ++kk) {
            float a[4], wv[4];
            #pragma unroll
            for (int i = 0; i < 4; ++i) a[i] = As[kk][ty + (i << 4)];
            #pragma unroll
            for (int j = 0; j < 4; ++j) wv[j] = Bs[kk][tx + (j << 4)];
            #pragma unroll
            for (int i = 0; i < 4; ++i)
                #pragma unroll
                for (int j = 0; j < 4; ++j)
                    acc[i][j] = fmaf(a[i], wv[j], acc[i][j]);
        }
    }
    #pragma unroll
    for (int j = 0; j < 4; ++j) {
        const float bj = bd[n0 + tx + (j << 4)];
        #pragma unroll
        for (int i = 0; i < 4; ++i)
            C[(size_t)(r0 + ty + (i << 4)) * Vv + n0 + tx + (j << 4)] = acc[i][j] + bj;
    }
}

// ---------------------------------------------------------------------------
// CE loss.
// ---------------------------------------------------------------------------
__global__ __launch_bounds__(256) void k_loss_row(
    const float* __restrict__ logits, const int* __restrict__ labels,
    float* __restrict__ partial)
{
    const int row = blockIdx.x;
    const float* lr = logits + (size_t)row * Vv;
    float m = -3.4e38f, s = 0.f;
    for (int i = threadIdx.x; i < Vv; i += 256) {
        float v = lr[i];
        float nm = fmaxf(m, v);
        s = s * expf(m - nm) + expf(v - nm);
        m = nm;
    }
    #pragma unroll
    for (int off = 1; off < 64; off <<= 1) {
        float om = __shfl_xor(m, off);
        float osv = __shfl_xor(s, off);
        float nm = fmaxf(m, om);
        s = s * expf(m - nm) + osv * expf(om - nm);
        m = nm;
    }
    __shared__ float lm[4], lsum[4];
    const int wid = threadIdx.x >> 6;
    if ((threadIdx.x & 63) == 0) { lm[wid] = m; lsum[wid] = s; }
    __syncthreads();
    if (threadIdx.x == 0) {
        float M = lm[0], Sv = lsum[0];
        #pragma unroll
        for (int ww = 1; ww < 4; ++ww) {
            float nm = fmaxf(M, lm[ww]);
            Sv = Sv * expf(M - nm) + lsum[ww] * expf(lm[ww] - nm);
            M = nm;
        }
        partial[row] = (M + logf(Sv)) - lr[labels[row]];
    }
}

__global__ __launch_bounds__(256) void k_loss_final(
    const float* __restrict__ partial, float* __restrict__ out0)
{
    float s = partial[threadIdx.x] + partial[threadIdx.x + 256]
            + partial[threadIdx.x + 512] + partial[threadIdx.x + 768];
    #pragma unroll
    for (int off = 1; off < 64; off <<= 1) s += __shfl_xor(s, off);
    __shared__ float red[4];
    if ((threadIdx.x & 63) == 0) red[threadIdx.x >> 6] = s;
    __syncthreads();
    if (threadIdx.x == 0) out0[0] = (red[0] + red[1] + red[2] + red[3]) * (1.f / NROWS);
}

// ---------------------------------------------------------------------------
extern "C" void kernel_launch(void* const* d_in, const int* in_sizes, int n_in,
                              void* d_out, int out_size, void* d_ws, size_t ws_size,
                              hipStream_t stream)
{
    const int*   labels  = (const int*)d_in[0];
    const float* emb     = (const float*)d_in[1];
    const float* W_in    = (const float*)d_in[2];
    const float* b_in    = (const float*)d_in[3];
    const float* W_sani  = (const float*)d_in[4];
    const float* b_sani  = (const float*)d_in[5];
    const float* ln_g    = (const float*)d_in[6];
    const float* ln_b    = (const float*)d_in[7];
    const float* W_dense = (const float*)d_in[8];
    const float* b_dense = (const float*)d_in[9];
    const float* ln2_g   = (const float*)d_in[10];
    const float* ln2_b   = (const float*)d_in[11];
    const float* W_dec   = (const float*)d_in[12];
    const float* b_dec   = (const float*)d_in[13];
    float* out    = (float*)d_out;
    float* logits = out + 1;

    const size_t NH = (size_t)NROWS * Hh;                 // 1M elems
    const size_t WDP_ELEMS = (size_t)32 * 2000 * 64 * 8;  // 32.768M bf16

    // out-scratch (dead before logits are written):
    float* S     = out + 8;
    float* hpf0  = S;                         // raw h f32 ping
    float* hpf1  = S + NH;                    // raw h f32 pong
    float* os    = S + 2 * NH;                // outputState f32
    float* ybf   = S + 3 * NH;                // head dense out
    bf16*  Wp0   = (bf16*)(S + 4 * NH);       // sani packed plain
    bf16*  Wp1   = (bf16*)(S + 5 * NH);       // sani packed * ln_g
    bf16*  hpb0  = (bf16*)(S + 6 * NH);       // raw h bf16 ping
    bf16*  hpb1  = hpb0 + NH;                 // raw h bf16 pong
    float* prt0  = S + 7 * NH;                // stats ping  [8*128*32]
    float* prt1  = prt0 + 8 * Ss * 32;        // stats pong
    float* cbias = prt1 + 8 * Ss * 32;        // folded bias [1024]

    const bool fast = ws_size >= WDP_ELEMS * 2 + NH * 2 + 8192;
    bf16 *Wdp = nullptr, *ybb = nullptr;
    float *yb, *pt;
    float* wsf = (float*)d_ws;
    if (fast) {
        Wdp = (bf16*)d_ws;
        ybb = Wdp + WDP_ELEMS;
        pt  = (float*)(ybb + NH);
        yb  = ybf;
    } else {
        yb = wsf;
        pt = wsf + NH;
    }

    k_pack2<<<dim3(64, 4), 256, 0, stream>>>(W_sani, Wp0, Hh, nullptr);
    k_pack2<<<dim3(64, 4), 256, 0, stream>>>(W_sani, Wp1, Hh, ln_g);
    k_cbias<<<4, 256, 0, stream>>>(W_sani, b_sani, ln_b, cbias);
    if (fast)
        k_pack2<<<dim3(32, 125), 256, 0, stream>>>(W_dec, Wdp, Vv, nullptr);

    hipMemsetAsync(os, 0, NH * sizeof(float), stream);   // rows 126/127 stay 0
    k_gemm1024<0><<<dim3(4, 64), 256, 0, stream>>>(labels, emb, W_in, b_in, hpf0, hpb0);

    for (int m = 0; m < Ss - 2; ++m) {
        const int src = m & 1;
        const int nt  = 126 - m;                 // rows m+1..126 (row 127 dead)
        const dim3 grid(16, (nt + 31) >> 5, Bb);
        const bf16*  hbA = src ? hpb1 : hpb0;
        const float* hfS = src ? hpf1 : hpf0;
        float* hfD = src ? hpf0 : hpf1;
        bf16*  hbD = src ? hpb0 : hpb1;
        const float* pR = src ? prt1 : prt0;
        float*       pW = src ? prt0 : prt1;
        if (m == 0)
            k_scan_fused<1><<<grid, 256, 0, stream>>>(hbA, hfS, hfD, hbD,
                Wp0, b_sani, pR, pW, ln_g, ln_b, m);
        else
            k_scan_fused<0><<<grid, 256, 0, stream>>>(hbA, hfS, hfD, hbD,
                Wp1, cbias, pR, pW, ln_g, ln_b, m);
    }

    k_finish_os<<<dim3(126, Bb), 256, 0, stream>>>(hpf0, hpf1, prt0, prt1,
                                                   ln_g, ln_b, os);

    k_gemm1024<1><<<dim3(4, 64), 256, 0, stream>>>(nullptr, os, W_dense, b_dense, yb, nullptr);
    k_ln_rows2<<<NROWS, 256, 0, stream>>>(yb, ln2_g, ln2_b, ybb);
    if (fast)
        k_dec_mm<<<dim3(250, 4), 512, 0, stream>>>(ybb, Wdp, b_dec, logits);
    else
        k_decoder<<<dim3(Vv / 64, NROWS / 64), 256, 0, stream>>>(yb, W_dec, b_dec, logits);
    k_loss_row<<<NROWS, 256, 0, stream>>>(logits, labels, pt);
    k_loss_final<<<1, 256, 0, stream>>>(pt, out);
}